// Round 5
// baseline (1022.496 us; speedup 1.0000x reference)
//
#include <hip/hip_runtime.h>
#include <stdint.h>

#define NB 32
#define NL 1024
#define ND 512
#define NTOP 13

typedef unsigned short u16;
typedef __bf16 bf16x8 __attribute__((ext_vector_type(8)));
typedef float f32x4 __attribute__((ext_vector_type(4)));

__device__ __forceinline__ u16 f2bf(float f) {
    union { float f; uint32_t u; } v; v.f = f;
    uint32_t r = v.u + 0x7fffu + ((v.u >> 16) & 1u);
    return (u16)(r >> 16);
}
__device__ __forceinline__ float bf2f(u16 h) {
    union { uint32_t u; float f; } v; v.u = ((uint32_t)h) << 16;
    return v.f;
}

__device__ __forceinline__ void gload16(const void* g, void* l) {
    __builtin_amdgcn_global_load_lds(
        (__attribute__((address_space(1))) void*)g,
        (__attribute__((address_space(3))) void*)l, 16, 0, 0);
}

// ---------------------------------------------------------------------------
// Unified MFMA tile kernel: C[m][n] = sum_k A[m][k] * Bt[n][k]  (K = ND = 512,
// all matrices row-major with inner stride ND).
// PASSES: 1 = plain bf16 (hi only); 3 = split hi/lo (hh + lh + hl).
// A_SRC/B_SRC: 0 = split-bf16 global buffers via global_load_lds;
//              1 = fp32 global, register-split during staging (ds_write).
// OUT_MODE: 0 = fp32 out; 1 = split bf16 out (Oh,Ol); 2 = bf16 out (Oh);
//           3 = correlation diag-reduce into mc (per blockIdx.z batch).
// HAS_BIAS: add bias[col].  RESID: 1 = add fp32 R[idx] (may alias Of:
//           same-thread read-then-write per element only).
// ---------------------------------------------------------------------------
template <int PASSES, int A_SRC, int B_SRC, int OUT_MODE, int HAS_BIAS, int RESID>
__global__ __launch_bounds__(256) void mm_mfma(
    const u16* __restrict__ Ah, const u16* __restrict__ Al, const float* __restrict__ Af,
    const u16* __restrict__ Bh, const u16* __restrict__ Bl, const float* __restrict__ Bf,
    const float* __restrict__ bias, const float* __restrict__ Rf,
    float* __restrict__ Of, u16* __restrict__ Oh, u16* __restrict__ Ol,
    float* __restrict__ mc)
{
    constexpr int NBUF = (PASSES == 3) ? 4 : 2;
    __shared__ u16 lds[NBUF][4096];   // [buf][row*32 + k], 8 KB each

    const int tid  = threadIdx.x;
    const int lane = tid & 63;
    const int wid  = tid >> 6;
    const int wr = wid >> 1, wc = wid & 1;

    const int n0 = blockIdx.x * 128;
    const int m0 = blockIdx.y * 128;
    const size_t boff = (size_t)blockIdx.z * NL * ND;   // 0 unless batched (corr)

    f32x4 acc[4][4];
#pragma unroll
    for (int m = 0; m < 4; ++m)
#pragma unroll
        for (int n = 0; n < 4; ++n) acc[m][n] = (f32x4){0.f, 0.f, 0.f, 0.f};

    const int srow = tid >> 2;        // 0..63
    const int scol = (tid & 3) * 8;   // k-offset in elements
    const int lo16 = lane & 15;
    const int hi16 = lane >> 4;

    for (int k0 = 0; k0 < ND; k0 += 32) {
#pragma unroll
        for (int i = 0; i < 2; ++i) {
            const int ro   = i * 64 + srow;
            const int ldso = i * 2048 + wid * 512;        // gload dest (elems)
            const int lin  = i * 2048 + srow * 32 + scol; // ds_write dest (elems)

            if constexpr (A_SRC == 0) {
                gload16(Ah + boff + (size_t)(m0 + ro) * ND + k0 + scol, &lds[0][ldso]);
                if constexpr (PASSES == 3)
                    gload16(Al + boff + (size_t)(m0 + ro) * ND + k0 + scol, &lds[2][ldso]);
            } else {
                const float* src = Af + boff + (size_t)(m0 + ro) * ND + k0 + scol;
                float4 v0 = *reinterpret_cast<const float4*>(src);
                float4 v1 = *reinterpret_cast<const float4*>(src + 4);
                float vv[8] = {v0.x, v0.y, v0.z, v0.w, v1.x, v1.y, v1.z, v1.w};
                uint32_t hw[4], lw[4];
#pragma unroll
                for (int j = 0; j < 4; ++j) {
                    u16 h0 = f2bf(vv[2 * j]), h1 = f2bf(vv[2 * j + 1]);
                    hw[j] = (uint32_t)h0 | ((uint32_t)h1 << 16);
                    if constexpr (PASSES == 3) {
                        u16 e0 = f2bf(vv[2 * j] - bf2f(h0));
                        u16 e1 = f2bf(vv[2 * j + 1] - bf2f(h1));
                        lw[j] = (uint32_t)e0 | ((uint32_t)e1 << 16);
                    }
                }
                *reinterpret_cast<uint4*>(&lds[0][lin]) = make_uint4(hw[0], hw[1], hw[2], hw[3]);
                if constexpr (PASSES == 3)
                    *reinterpret_cast<uint4*>(&lds[2][lin]) = make_uint4(lw[0], lw[1], lw[2], lw[3]);
            }

            if constexpr (B_SRC == 0) {
                gload16(Bh + boff + (size_t)(n0 + ro) * ND + k0 + scol, &lds[1][ldso]);
                if constexpr (PASSES == 3)
                    gload16(Bl + boff + (size_t)(n0 + ro) * ND + k0 + scol, &lds[3][ldso]);
            } else {
                const float* src = Bf + boff + (size_t)(n0 + ro) * ND + k0 + scol;
                float4 v0 = *reinterpret_cast<const float4*>(src);
                float4 v1 = *reinterpret_cast<const float4*>(src + 4);
                float vv[8] = {v0.x, v0.y, v0.z, v0.w, v1.x, v1.y, v1.z, v1.w};
                uint32_t hw[4], lw[4];
#pragma unroll
                for (int j = 0; j < 4; ++j) {
                    u16 h0 = f2bf(vv[2 * j]), h1 = f2bf(vv[2 * j + 1]);
                    hw[j] = (uint32_t)h0 | ((uint32_t)h1 << 16);
                    if constexpr (PASSES == 3) {
                        u16 e0 = f2bf(vv[2 * j] - bf2f(h0));
                        u16 e1 = f2bf(vv[2 * j + 1] - bf2f(h1));
                        lw[j] = (uint32_t)e0 | ((uint32_t)e1 << 16);
                    }
                }
                *reinterpret_cast<uint4*>(&lds[1][lin]) = make_uint4(hw[0], hw[1], hw[2], hw[3]);
                if constexpr (PASSES == 3)
                    *reinterpret_cast<uint4*>(&lds[3][lin]) = make_uint4(lw[0], lw[1], lw[2], lw[3]);
            }
        }
        __syncthreads();

        bf16x8 ah[4], bh[4], al[4], bl[4];
#pragma unroll
        for (int m = 0; m < 4; ++m) {
            const int off = (wr * 64 + m * 16 + lo16) * 32 + hi16 * 8;
            ah[m] = *reinterpret_cast<const bf16x8*>(&lds[0][off]);
            if constexpr (PASSES == 3)
                al[m] = *reinterpret_cast<const bf16x8*>(&lds[2][off]);
        }
#pragma unroll
        for (int n = 0; n < 4; ++n) {
            const int off = (wc * 64 + n * 16 + lo16) * 32 + hi16 * 8;
            bh[n] = *reinterpret_cast<const bf16x8*>(&lds[1][off]);
            if constexpr (PASSES == 3)
                bl[n] = *reinterpret_cast<const bf16x8*>(&lds[3][off]);
        }
#pragma unroll
        for (int m = 0; m < 4; ++m)
#pragma unroll
            for (int n = 0; n < 4; ++n) {
                acc[m][n] = __builtin_amdgcn_mfma_f32_16x16x32_bf16(ah[m], bh[n], acc[m][n], 0, 0, 0);
                if constexpr (PASSES == 3) {
                    acc[m][n] = __builtin_amdgcn_mfma_f32_16x16x32_bf16(al[m], bh[n], acc[m][n], 0, 0, 0);
                    acc[m][n] = __builtin_amdgcn_mfma_f32_16x16x32_bf16(ah[m], bl[n], acc[m][n], 0, 0, 0);
                }
            }
        __syncthreads();
    }

    if constexpr (OUT_MODE == 3) {
        float* diag = reinterpret_cast<float*>(&lds[0][0]);  // 4 KB scratch
        for (int s = tid; s < NL; s += 256) diag[s] = 0.f;
        __syncthreads();
#pragma unroll
        for (int m = 0; m < 4; ++m)
#pragma unroll
            for (int n = 0; n < 4; ++n)
#pragma unroll
                for (int r = 0; r < 4; ++r) {
                    int row = m0 + wr * 64 + m * 16 + hi16 * 4 + r;
                    int col = n0 + wc * 64 + n * 16 + lo16;
                    atomicAdd(&diag[(row - col) & (NL - 1)], acc[m][n][r]);
                }
        __syncthreads();
        const int base = (m0 - n0 - 127) & (NL - 1);
        float* mcb = mc + (size_t)blockIdx.z * NL;
        for (int o = tid; o < 255; o += 256) {
            int tau = (base + o) & (NL - 1);
            atomicAdd(&mcb[tau], diag[tau] * (1.0f / (float)ND));
        }
    } else {
#pragma unroll
        for (int m = 0; m < 4; ++m)
#pragma unroll
            for (int n = 0; n < 4; ++n)
#pragma unroll
                for (int r = 0; r < 4; ++r) {
                    const int row = m0 + wr * 64 + m * 16 + hi16 * 4 + r;
                    const int col = n0 + wc * 64 + n * 16 + lo16;
                    const size_t idx = (size_t)row * ND + col;
                    float v = acc[m][n][r];
                    if constexpr (HAS_BIAS) v += bias[col];
                    if constexpr (RESID == 1) v += Rf[idx];
                    if constexpr (OUT_MODE == 0) {
                        Of[idx] = v;
                    } else if constexpr (OUT_MODE == 1) {
                        u16 h = f2bf(v);
                        Oh[idx] = h;
                        Ol[idx] = f2bf(v - bf2f(h));
                    } else {
                        Oh[idx] = f2bf(v);
                    }
                }
    }
}

// ---------------------------------------------------------------------------
// Weight prep. w==0: Wq split UNtransposed (rows = input dim, cols = output).
// w==1: Wk split UNtransposed (M-GEMM contracts over the OUTPUT dim of both).
// w==2/3/4: Wv/Wo/Wd transposed hi-only (B-operands of x@W GEMMs).
// ---------------------------------------------------------------------------
__global__ __launch_bounds__(256) void prep_weights(
    const float* __restrict__ Wq, const float* __restrict__ Wk,
    const float* __restrict__ Wv, const float* __restrict__ Wo,
    const float* __restrict__ Wd,
    u16* __restrict__ wq_h, u16* __restrict__ wq_l,
    u16* __restrict__ wk_h, u16* __restrict__ wk_l,
    u16* __restrict__ wvt_h, u16* __restrict__ wot_h, u16* __restrict__ wdt_h)
{
    const int idx = blockIdx.x * 256 + threadIdx.x;   // 0..262143
    const int w = blockIdx.y;
    if (w == 0) {
        float val = Wq[idx];
        u16 h = f2bf(val);
        wq_h[idx] = h; wq_l[idx] = f2bf(val - bf2f(h));
    } else if (w == 1) {
        float val = Wk[idx];
        u16 h = f2bf(val);
        wk_h[idx] = h; wk_l[idx] = f2bf(val - bf2f(h));
    } else {
        const int n = idx >> 9;
        const int k = idx & (ND - 1);
        const float* W = (w == 2) ? Wv : (w == 3) ? Wo : Wd;
        float val = W[(size_t)k * ND + n];
        u16 h = f2bf(val);
        if (w == 2)      { wvt_h[idx] = h; }
        else if (w == 3) { wot_h[idx] = h; }
        else             { wdt_h[idx] = h; }
    }
}

// ---------------------------------------------------------------------------
// Per-batch top-13 (argmax iteration, ties -> lower index) + softmax.
// ---------------------------------------------------------------------------
__global__ __launch_bounds__(256) void topk_softmax(
    const float* __restrict__ mc, float* __restrict__ wout, int* __restrict__ dout)
{
    const int tid = threadIdx.x;
    const int b = blockIdx.x;
    __shared__ float vals[NL];
    __shared__ float rv[256];
    __shared__ int   ri[256];
    __shared__ float topv[NTOP];
    __shared__ int   topi[NTOP];

    for (int s = tid; s < NL; s += 256) vals[s] = mc[b * NL + s];
    __syncthreads();

    for (int it = 0; it < NTOP; ++it) {
        float bv = -3.402823466e38f;
        int bi = 1 << 30;
        for (int s = tid; s < NL; s += 256) {
            float vv = vals[s];
            if (vv > bv || (vv == bv && s < bi)) { bv = vv; bi = s; }
        }
        rv[tid] = bv; ri[tid] = bi;
        __syncthreads();
        for (int off = 128; off > 0; off >>= 1) {
            if (tid < off) {
                float ov = rv[tid + off]; int oi = ri[tid + off];
                if (ov > rv[tid] || (ov == rv[tid] && oi < ri[tid])) { rv[tid] = ov; ri[tid] = oi; }
            }
            __syncthreads();
        }
        if (tid == 0) { topv[it] = rv[0]; topi[it] = ri[0]; vals[ri[0]] = -3.402823466e38f; }
        __syncthreads();
    }

    if (tid == 0) {
        float m = topv[0];
        float e[NTOP];
        float ssum = 0.f;
        for (int i = 0; i < NTOP; ++i) { e[i] = expf(topv[i] - m); ssum += e[i]; }
        float inv = 1.0f / ssum;
        for (int i = 0; i < NTOP; ++i) {
            wout[b * 16 + i] = e[i] * inv;
            dout[b * 16 + i] = topi[i];
        }
    }
}

// ---------------------------------------------------------------------------
// agg[b,t,c] = sum_i w[b,i] * v[b,(t+delay[b,i])%L, c]; v & agg bf16.
// ---------------------------------------------------------------------------
__global__ __launch_bounds__(256) void aggregate(
    const u16* __restrict__ v, const float* __restrict__ wts,
    const int* __restrict__ dly, u16* __restrict__ out)
{
    const int tid = threadIdx.x;
    const int b = blockIdx.y;
    const int t = blockIdx.x * 4 + (tid >> 6);
    const int c8 = tid & 63;
    const uint4* vb = reinterpret_cast<const uint4*>(v + (size_t)b * NL * ND);
    float acc[8] = {0.f};
#pragma unroll
    for (int i = 0; i < NTOP; ++i) {
        const int s = (t + dly[b * 16 + i]) & (NL - 1);
        const float wi = wts[b * 16 + i];
        uint4 p = vb[(size_t)s * 64 + c8];
        const uint32_t pw[4] = {p.x, p.y, p.z, p.w};
#pragma unroll
        for (int j = 0; j < 4; ++j) {
            acc[2 * j]     = fmaf(wi, bf2f((u16)(pw[j] & 0xffff)), acc[2 * j]);
            acc[2 * j + 1] = fmaf(wi, bf2f((u16)(pw[j] >> 16)),    acc[2 * j + 1]);
        }
    }
    uint32_t o[4];
#pragma unroll
    for (int j = 0; j < 4; ++j)
        o[j] = (uint32_t)f2bf(acc[2 * j]) | ((uint32_t)f2bf(acc[2 * j + 1]) << 16);
    reinterpret_cast<uint4*>(out + (size_t)b * NL * ND)[(size_t)t * 64 + c8] =
        make_uint4(o[0], o[1], o[2], o[3]);
}

// ---------------------------------------------------------------------------
// IN-PLACE series decomp: io[t] -= moving_avg_25(io[t]) (TF 'SAME' counts).
// Each block owns one float4 channel column of one batch (race-free in-place).
// WRITE_BF: also emit bf16(hi) copy for the next GEMM's A operand.
// ---------------------------------------------------------------------------
template <int WRITE_BF>
__global__ __launch_bounds__(256) void movavg_ip(
    float* __restrict__ io, u16* __restrict__ outh)
{
    __shared__ float4 col[NL];   // 16 KB
    const int tid = threadIdx.x;
    const int c4 = blockIdx.x;   // 0..127 (float4 channel group)
    const int b  = blockIdx.y;
    float4* iob = reinterpret_cast<float4*>(io + (size_t)b * NL * ND) + c4;
    for (int t = tid; t < NL; t += 256) col[t] = iob[(size_t)t * 128];
    __syncthreads();
    for (int t = tid; t < NL; t += 256) {
        const int lo = (t - 12 < 0) ? 0 : t - 12;
        const int hi = (t + 12 > NL - 1) ? NL - 1 : t + 12;
        float4 s = {0.f, 0.f, 0.f, 0.f};
        for (int u = lo; u <= hi; ++u) {
            float4 p = col[u];
            s.x += p.x; s.y += p.y; s.z += p.z; s.w += p.w;
        }
        const float inv = 1.0f / (float)(hi - lo + 1);
        float4 c = col[t];
        float4 o = {c.x - s.x * inv, c.y - s.y * inv, c.z - s.z * inv, c.w - s.w * inv};
        iob[(size_t)t * 128] = o;
        if constexpr (WRITE_BF) {
            ushort4 hh;
            hh.x = f2bf(o.x); hh.y = f2bf(o.y); hh.z = f2bf(o.z); hh.w = f2bf(o.w);
            reinterpret_cast<ushort4*>(outh + (size_t)b * NL * ND)[(size_t)t * 128 + c4] = hh;
        }
    }
}

// ---------------------------------------------------------------------------
extern "C" void kernel_launch(void* const* d_in, const int* in_sizes, int n_in,
                              void* d_out, int out_size, void* d_ws, size_t ws_size,
                              hipStream_t stream)
{
    const float* x  = (const float*)d_in[0];
    const float* Wq = (const float*)d_in[1];
    const float* bq = (const float*)d_in[2];  (void)bq;  // bias terms are
    const float* Wk = (const float*)d_in[3];             // tau-independent ->
    const float* bk = (const float*)d_in[4];  (void)bk;  // drop out of topk+softmax
    const float* Wv = (const float*)d_in[5];
    const float* bv = (const float*)d_in[6];
    const float* Wo = (const float*)d_in[7];
    const float* bo = (const float*)d_in[8];
    const float* Wd = (const float*)d_in[9];
    const float* bd = (const float*)d_in[10];
    float* out = (float*)d_out;

    // ---- workspace layout: 70 MiB total ----
    const size_t MBy = 1024ull * 1024ull;
    char* ws = (char*)d_ws;
    float* mc  = (float*)(ws);                 // 128 KB
    float* wts = (float*)(ws + 131072);        // 2 KB
    int*   dly = (int*)  (ws + 133120);        // 2 KB
    u16* Wq_h  = (u16*)(ws + 1 * MBy);
    u16* Wq_l  = (u16*)(ws + 1 * MBy + 512 * 1024);
    u16* Wk_h  = (u16*)(ws + 2 * MBy);
    u16* Wk_l  = (u16*)(ws + 2 * MBy + 512 * 1024);
    u16* Wvt_h = (u16*)(ws + 3 * MBy);
    u16* Wot_h = (u16*)(ws + 3 * MBy + 512 * 1024);
    u16* Wdt_h = (u16*)(ws + 4 * MBy);
    u16* Mt_h  = (u16*)(ws + 4 * MBy + 512 * 1024);
    u16* Mt_l  = (u16*)(ws + 5 * MBy);
    u16* ph    = (u16*)(ws + 6 * MBy);         // 32 MiB: P-hi -> v_bf -> x1s_bf
    u16* pl    = (u16*)(ws + 38 * MBy);        // 32 MiB: P-lo -> agg_bf
    u16* v_bf   = ph;
    u16* agg_bf = pl;
    u16* xsh    = ph;

    hipMemsetAsync(mc, 0, (size_t)NB * NL * sizeof(float), stream);

    prep_weights<<<dim3((ND * ND) / 256, 5), 256, 0, stream>>>(
        Wq, Wk, Wv, Wo, Wd, Wq_h, Wq_l, Wk_h, Wk_l, Wvt_h, Wot_h, Wdt_h);

    // Mt[f][e] = sum_c Wk[f][c]*Wq[e][c]  (both operands AS STORED), split out
    mm_mfma<3, 0, 0, 1, 0, 0><<<dim3(4, 4), 256, 0, stream>>>(
        Wk_h, Wk_l, nullptr, Wq_h, Wq_l, nullptr,
        nullptr, nullptr, nullptr, Mt_h, Mt_l, nullptr);

    const dim3 gg(ND / 128, (NB * NL) / 128);   // (4, 256)

    // P = x @ M  (A: fp32 x reg-split; B: Mt split) -> ph/pl
    mm_mfma<3, 1, 0, 1, 0, 0><<<gg, 256, 0, stream>>>(
        nullptr, nullptr, x, Mt_h, Mt_l, nullptr,
        nullptr, nullptr, nullptr, ph, pl, nullptr);

    // mean_corr: diag-reduce of P_b @ X_b^T (A: ph/pl; B: fp32 x reg-split)
    mm_mfma<3, 0, 1, 3, 0, 0><<<dim3(NL / 128, NL / 128, NB), 256, 0, stream>>>(
        ph, pl, nullptr, nullptr, nullptr, x,
        nullptr, nullptr, nullptr, nullptr, nullptr, mc);

    topk_softmax<<<NB, 256, 0, stream>>>(mc, wts, dly);

    // v = x @ Wv + bv -> v_bf (reuses ph; P dead after corr)
    mm_mfma<1, 1, 0, 2, 1, 0><<<gg, 256, 0, stream>>>(
        nullptr, nullptr, x, Wvt_h, nullptr, nullptr,
        bv, nullptr, nullptr, v_bf, nullptr, nullptr);

    // agg -> agg_bf (reuses pl)
    aggregate<<<dim3(NL / 4, NB), 256, 0, stream>>>(v_bf, wts, dly, agg_bf);

    // x1 = agg @ Wo + bo + x -> d_out (fp32)
    mm_mfma<1, 0, 0, 0, 1, 1><<<gg, 256, 0, stream>>>(
        agg_bf, nullptr, nullptr, Wot_h, nullptr, nullptr,
        bo, x, out, nullptr, nullptr, nullptr);

    // x1s = x1 - movavg(x1): in-place on d_out, bf16 copy -> xsh (v dead)
    movavg_ip<1><<<dim3(128, NB), 256, 0, stream>>>(out, xsh);

    // x2 = x1s @ Wd + bd + x1s: A = xsh (bf16), residual = d_out (fp32),
    // written back to d_out (same-thread read-then-write per element: safe)
    mm_mfma<1, 0, 0, 0, 1, 1><<<gg, 256, 0, stream>>>(
        xsh, nullptr, nullptr, Wdt_h, nullptr, nullptr,
        bd, out, out, nullptr, nullptr, nullptr);

    // out = x2 - movavg(x2): in-place on d_out
    movavg_ip<0><<<dim3(128, NB), 256, 0, stream>>>(out, nullptr);
}

// Round 6
// 1016.873 us; speedup vs baseline: 1.0055x; 1.0055x over previous
//
#include <hip/hip_runtime.h>
#include <stdint.h>

#define NB 32
#define NL 1024
#define ND 512
#define NTOP 13

typedef unsigned short u16;
typedef __bf16 bf16x8 __attribute__((ext_vector_type(8)));
typedef float f32x4 __attribute__((ext_vector_type(4)));

__device__ __forceinline__ u16 f2bf(float f) {
    union { float f; uint32_t u; } v; v.f = f;
    uint32_t r = v.u + 0x7fffu + ((v.u >> 16) & 1u);
    return (u16)(r >> 16);
}
__device__ __forceinline__ float bf2f(u16 h) {
    union { uint32_t u; float f; } v; v.u = ((uint32_t)h) << 16;
    return v.f;
}

__device__ __forceinline__ void gload16(const void* g, void* l) {
    __builtin_amdgcn_global_load_lds(
        (__attribute__((address_space(1))) void*)g,
        (__attribute__((address_space(3))) void*)l, 16, 0, 0);
}

// ---------------------------------------------------------------------------
// Unified MFMA tile kernel: C[m][n] = sum_k A[m][k] * Bt[n][k]  (K = ND = 512,
// all matrices row-major with inner stride ND).
//
// LDS layout is XOR-swizzled to kill the 8-way ds_read_b128 bank conflict:
// logical 16B column c16 of row r lives at slot c16 ^ ((r>>1)&3).  Writes stay
// LINEAR (global_load_lds requires wave-uniform base + lane*16); instead the
// per-lane GLOBAL source column is pre-swizzled (both-sides-or-neither rule).
//
// PASSES: 1 = plain bf16 (hi only); 3 = split hi/lo (hh + lh + hl).
// A_SRC/B_SRC: 0 = split-bf16 global buffers via global_load_lds;
//              1 = fp32 global, register-split during staging (ds_write).
// OUT_MODE: 0 = fp32 out; 1 = split bf16 out (Oh,Ol); 2 = bf16 out (Oh);
//           3 = correlation diag-reduce into mc (per blockIdx.z batch).
// HAS_BIAS: add bias[col].  RESID: 1 = add fp32 R[idx] (may alias Of:
//           same-thread read-then-write per element only).
// ---------------------------------------------------------------------------
template <int PASSES, int A_SRC, int B_SRC, int OUT_MODE, int HAS_BIAS, int RESID>
__global__ __launch_bounds__(256) void mm_mfma(
    const u16* __restrict__ Ah, const u16* __restrict__ Al, const float* __restrict__ Af,
    const u16* __restrict__ Bh, const u16* __restrict__ Bl, const float* __restrict__ Bf,
    const float* __restrict__ bias, const float* __restrict__ Rf,
    float* __restrict__ Of, u16* __restrict__ Oh, u16* __restrict__ Ol,
    float* __restrict__ mc)
{
    constexpr int NBUF = (PASSES == 3) ? 4 : 2;
    __shared__ u16 lds[NBUF][4096];   // [buf][row*32 + c16*8], 8 KB each

    const int tid  = threadIdx.x;
    const int lane = tid & 63;
    const int wid  = tid >> 6;
    const int wr = wid >> 1, wc = wid & 1;

    const int n0 = blockIdx.x * 128;
    const int m0 = blockIdx.y * 128;
    const size_t boff = (size_t)blockIdx.z * NL * ND;   // 0 unless batched (corr)

    f32x4 acc[4][4];
#pragma unroll
    for (int m = 0; m < 4; ++m)
#pragma unroll
        for (int n = 0; n < 4; ++n) acc[m][n] = (f32x4){0.f, 0.f, 0.f, 0.f};

    const int srow = tid >> 2;                       // 0..63 (staging row)
    const int c16s = tid & 3;                        // LDS slot column (linear)
    const int scol = ((c16s ^ ((tid >> 3) & 3)) * 8); // swizzled SOURCE col (elems)
    const int lo16 = lane & 15;
    const int hi16 = lane >> 4;
    const int c16r = hi16 ^ ((lo16 >> 1) & 3);       // swizzled READ slot

    for (int k0 = 0; k0 < ND; k0 += 32) {
#pragma unroll
        for (int i = 0; i < 2; ++i) {
            const int ro   = i * 64 + srow;
            const int ldso = i * 2048 + wid * 512;             // gload dest (elems)
            const int lin  = i * 2048 + srow * 32 + c16s * 8;  // ds_write dest (elems)

            if constexpr (A_SRC == 0) {
                gload16(Ah + boff + (size_t)(m0 + ro) * ND + k0 + scol, &lds[0][ldso]);
                if constexpr (PASSES == 3)
                    gload16(Al + boff + (size_t)(m0 + ro) * ND + k0 + scol, &lds[2][ldso]);
            } else {
                const float* src = Af + boff + (size_t)(m0 + ro) * ND + k0 + scol;
                float4 v0 = *reinterpret_cast<const float4*>(src);
                float4 v1 = *reinterpret_cast<const float4*>(src + 4);
                float vv[8] = {v0.x, v0.y, v0.z, v0.w, v1.x, v1.y, v1.z, v1.w};
                uint32_t hw[4], lw[4];
#pragma unroll
                for (int j = 0; j < 4; ++j) {
                    u16 h0 = f2bf(vv[2 * j]), h1 = f2bf(vv[2 * j + 1]);
                    hw[j] = (uint32_t)h0 | ((uint32_t)h1 << 16);
                    if constexpr (PASSES == 3) {
                        u16 e0 = f2bf(vv[2 * j] - bf2f(h0));
                        u16 e1 = f2bf(vv[2 * j + 1] - bf2f(h1));
                        lw[j] = (uint32_t)e0 | ((uint32_t)e1 << 16);
                    }
                }
                *reinterpret_cast<uint4*>(&lds[0][lin]) = make_uint4(hw[0], hw[1], hw[2], hw[3]);
                if constexpr (PASSES == 3)
                    *reinterpret_cast<uint4*>(&lds[2][lin]) = make_uint4(lw[0], lw[1], lw[2], lw[3]);
            }

            if constexpr (B_SRC == 0) {
                gload16(Bh + boff + (size_t)(n0 + ro) * ND + k0 + scol, &lds[1][ldso]);
                if constexpr (PASSES == 3)
                    gload16(Bl + boff + (size_t)(n0 + ro) * ND + k0 + scol, &lds[3][ldso]);
            } else {
                const float* src = Bf + boff + (size_t)(n0 + ro) * ND + k0 + scol;
                float4 v0 = *reinterpret_cast<const float4*>(src);
                float4 v1 = *reinterpret_cast<const float4*>(src + 4);
                float vv[8] = {v0.x, v0.y, v0.z, v0.w, v1.x, v1.y, v1.z, v1.w};
                uint32_t hw[4], lw[4];
#pragma unroll
                for (int j = 0; j < 4; ++j) {
                    u16 h0 = f2bf(vv[2 * j]), h1 = f2bf(vv[2 * j + 1]);
                    hw[j] = (uint32_t)h0 | ((uint32_t)h1 << 16);
                    if constexpr (PASSES == 3) {
                        u16 e0 = f2bf(vv[2 * j] - bf2f(h0));
                        u16 e1 = f2bf(vv[2 * j + 1] - bf2f(h1));
                        lw[j] = (uint32_t)e0 | ((uint32_t)e1 << 16);
                    }
                }
                *reinterpret_cast<uint4*>(&lds[1][lin]) = make_uint4(hw[0], hw[1], hw[2], hw[3]);
                if constexpr (PASSES == 3)
                    *reinterpret_cast<uint4*>(&lds[3][lin]) = make_uint4(lw[0], lw[1], lw[2], lw[3]);
            }
        }
        __syncthreads();

        bf16x8 ah[4], bh[4], al[4], bl[4];
#pragma unroll
        for (int m = 0; m < 4; ++m) {
            const int off = (wr * 64 + m * 16 + lo16) * 32 + c16r * 8;
            ah[m] = *reinterpret_cast<const bf16x8*>(&lds[0][off]);
            if constexpr (PASSES == 3)
                al[m] = *reinterpret_cast<const bf16x8*>(&lds[2][off]);
        }
#pragma unroll
        for (int n = 0; n < 4; ++n) {
            const int off = (wc * 64 + n * 16 + lo16) * 32 + c16r * 8;
            bh[n] = *reinterpret_cast<const bf16x8*>(&lds[1][off]);
            if constexpr (PASSES == 3)
                bl[n] = *reinterpret_cast<const bf16x8*>(&lds[3][off]);
        }
#pragma unroll
        for (int m = 0; m < 4; ++m)
#pragma unroll
            for (int n = 0; n < 4; ++n) {
                acc[m][n] = __builtin_amdgcn_mfma_f32_16x16x32_bf16(ah[m], bh[n], acc[m][n], 0, 0, 0);
                if constexpr (PASSES == 3) {
                    acc[m][n] = __builtin_amdgcn_mfma_f32_16x16x32_bf16(al[m], bh[n], acc[m][n], 0, 0, 0);
                    acc[m][n] = __builtin_amdgcn_mfma_f32_16x16x32_bf16(ah[m], bl[n], acc[m][n], 0, 0, 0);
                }
            }
        __syncthreads();
    }

    if constexpr (OUT_MODE == 3) {
        float* diag = reinterpret_cast<float*>(&lds[0][0]);  // 4 KB scratch
        for (int s = tid; s < NL; s += 256) diag[s] = 0.f;
        __syncthreads();
#pragma unroll
        for (int m = 0; m < 4; ++m)
#pragma unroll
            for (int n = 0; n < 4; ++n)
#pragma unroll
                for (int r = 0; r < 4; ++r) {
                    int row = m0 + wr * 64 + m * 16 + hi16 * 4 + r;
                    int col = n0 + wc * 64 + n * 16 + lo16;
                    atomicAdd(&diag[(row - col) & (NL - 1)], acc[m][n][r]);
                }
        __syncthreads();
        const int base = (m0 - n0 - 127) & (NL - 1);
        float* mcb = mc + (size_t)blockIdx.z * NL;
        for (int o = tid; o < 255; o += 256) {
            int tau = (base + o) & (NL - 1);
            atomicAdd(&mcb[tau], diag[tau] * (1.0f / (float)ND));
        }
    } else {
#pragma unroll
        for (int m = 0; m < 4; ++m)
#pragma unroll
            for (int n = 0; n < 4; ++n)
#pragma unroll
                for (int r = 0; r < 4; ++r) {
                    const int row = m0 + wr * 64 + m * 16 + hi16 * 4 + r;
                    const int col = n0 + wc * 64 + n * 16 + lo16;
                    const size_t idx = (size_t)row * ND + col;
                    float v = acc[m][n][r];
                    if constexpr (HAS_BIAS) v += bias[col];
                    if constexpr (RESID == 1) v += Rf[idx];
                    if constexpr (OUT_MODE == 0) {
                        Of[idx] = v;
                    } else if constexpr (OUT_MODE == 1) {
                        u16 h = f2bf(v);
                        Oh[idx] = h;
                        Ol[idx] = f2bf(v - bf2f(h));
                    } else {
                        Oh[idx] = f2bf(v);
                    }
                }
    }
}

// ---------------------------------------------------------------------------
// Weight prep. w==0: Wq split UNtransposed (rows = input dim, cols = output).
// w==1: Wk split UNtransposed (M-GEMM contracts over the OUTPUT dim of both).
// w==2/3/4: Wv/Wo/Wd transposed hi-only (B-operands of x@W GEMMs).
// ---------------------------------------------------------------------------
__global__ __launch_bounds__(256) void prep_weights(
    const float* __restrict__ Wq, const float* __restrict__ Wk,
    const float* __restrict__ Wv, const float* __restrict__ Wo,
    const float* __restrict__ Wd,
    u16* __restrict__ wq_h, u16* __restrict__ wq_l,
    u16* __restrict__ wk_h, u16* __restrict__ wk_l,
    u16* __restrict__ wvt_h, u16* __restrict__ wot_h, u16* __restrict__ wdt_h)
{
    const int idx = blockIdx.x * 256 + threadIdx.x;   // 0..262143
    const int w = blockIdx.y;
    if (w == 0) {
        float val = Wq[idx];
        u16 h = f2bf(val);
        wq_h[idx] = h; wq_l[idx] = f2bf(val - bf2f(h));
    } else if (w == 1) {
        float val = Wk[idx];
        u16 h = f2bf(val);
        wk_h[idx] = h; wk_l[idx] = f2bf(val - bf2f(h));
    } else {
        const int n = idx >> 9;
        const int k = idx & (ND - 1);
        const float* W = (w == 2) ? Wv : (w == 3) ? Wo : Wd;
        float val = W[(size_t)k * ND + n];
        u16 h = f2bf(val);
        if (w == 2)      { wvt_h[idx] = h; }
        else if (w == 3) { wot_h[idx] = h; }
        else             { wdt_h[idx] = h; }
    }
}

// ---------------------------------------------------------------------------
// Per-batch top-13 (argmax iteration, ties -> lower index) + softmax.
// ---------------------------------------------------------------------------
__global__ __launch_bounds__(256) void topk_softmax(
    const float* __restrict__ mc, float* __restrict__ wout, int* __restrict__ dout)
{
    const int tid = threadIdx.x;
    const int b = blockIdx.x;
    __shared__ float vals[NL];
    __shared__ float rv[256];
    __shared__ int   ri[256];
    __shared__ float topv[NTOP];
    __shared__ int   topi[NTOP];

    for (int s = tid; s < NL; s += 256) vals[s] = mc[b * NL + s];
    __syncthreads();

    for (int it = 0; it < NTOP; ++it) {
        float bv = -3.402823466e38f;
        int bi = 1 << 30;
        for (int s = tid; s < NL; s += 256) {
            float vv = vals[s];
            if (vv > bv || (vv == bv && s < bi)) { bv = vv; bi = s; }
        }
        rv[tid] = bv; ri[tid] = bi;
        __syncthreads();
        for (int off = 128; off > 0; off >>= 1) {
            if (tid < off) {
                float ov = rv[tid + off]; int oi = ri[tid + off];
                if (ov > rv[tid] || (ov == rv[tid] && oi < ri[tid])) { rv[tid] = ov; ri[tid] = oi; }
            }
            __syncthreads();
        }
        if (tid == 0) { topv[it] = rv[0]; topi[it] = ri[0]; vals[ri[0]] = -3.402823466e38f; }
        __syncthreads();
    }

    if (tid == 0) {
        float m = topv[0];
        float e[NTOP];
        float ssum = 0.f;
        for (int i = 0; i < NTOP; ++i) { e[i] = expf(topv[i] - m); ssum += e[i]; }
        float inv = 1.0f / ssum;
        for (int i = 0; i < NTOP; ++i) {
            wout[b * 16 + i] = e[i] * inv;
            dout[b * 16 + i] = topi[i];
        }
    }
}

// ---------------------------------------------------------------------------
// agg[b,t,c] = sum_i w[b,i] * v[b,(t+delay[b,i])%L, c]; v & agg bf16.
// ---------------------------------------------------------------------------
__global__ __launch_bounds__(256) void aggregate(
    const u16* __restrict__ v, const float* __restrict__ wts,
    const int* __restrict__ dly, u16* __restrict__ out)
{
    const int tid = threadIdx.x;
    const int b = blockIdx.y;
    const int t = blockIdx.x * 4 + (tid >> 6);
    const int c8 = tid & 63;
    const uint4* vb = reinterpret_cast<const uint4*>(v + (size_t)b * NL * ND);
    float acc[8] = {0.f};
#pragma unroll
    for (int i = 0; i < NTOP; ++i) {
        const int s = (t + dly[b * 16 + i]) & (NL - 1);
        const float wi = wts[b * 16 + i];
        uint4 p = vb[(size_t)s * 64 + c8];
        const uint32_t pw[4] = {p.x, p.y, p.z, p.w};
#pragma unroll
        for (int j = 0; j < 4; ++j) {
            acc[2 * j]     = fmaf(wi, bf2f((u16)(pw[j] & 0xffff)), acc[2 * j]);
            acc[2 * j + 1] = fmaf(wi, bf2f((u16)(pw[j] >> 16)),    acc[2 * j + 1]);
        }
    }
    uint32_t o[4];
#pragma unroll
    for (int j = 0; j < 4; ++j)
        o[j] = (uint32_t)f2bf(acc[2 * j]) | ((uint32_t)f2bf(acc[2 * j + 1]) << 16);
    reinterpret_cast<uint4*>(out + (size_t)b * NL * ND)[(size_t)t * 64 + c8] =
        make_uint4(o[0], o[1], o[2], o[3]);
}

// ---------------------------------------------------------------------------
// IN-PLACE series decomp: io[t] -= moving_avg_25(io[t]) (TF 'SAME' counts).
// Each block owns one float4 channel column of one batch (race-free in-place).
// WRITE_BF: also emit bf16(hi) copy for the next GEMM's A operand.
// ---------------------------------------------------------------------------
template <int WRITE_BF>
__global__ __launch_bounds__(256) void movavg_ip(
    float* __restrict__ io, u16* __restrict__ outh)
{
    __shared__ float4 col[NL];   // 16 KB
    const int tid = threadIdx.x;
    const int c4 = blockIdx.x;   // 0..127 (float4 channel group)
    const int b  = blockIdx.y;
    float4* iob = reinterpret_cast<float4*>(io + (size_t)b * NL * ND) + c4;
    for (int t = tid; t < NL; t += 256) col[t] = iob[(size_t)t * 128];
    __syncthreads();
    for (int t = tid; t < NL; t += 256) {
        const int lo = (t - 12 < 0) ? 0 : t - 12;
        const int hi = (t + 12 > NL - 1) ? NL - 1 : t + 12;
        float4 s = {0.f, 0.f, 0.f, 0.f};
        for (int u = lo; u <= hi; ++u) {
            float4 p = col[u];
            s.x += p.x; s.y += p.y; s.z += p.z; s.w += p.w;
        }
        const float inv = 1.0f / (float)(hi - lo + 1);
        float4 c = col[t];
        float4 o = {c.x - s.x * inv, c.y - s.y * inv, c.z - s.z * inv, c.w - s.w * inv};
        iob[(size_t)t * 128] = o;
        if constexpr (WRITE_BF) {
            ushort4 hh;
            hh.x = f2bf(o.x); hh.y = f2bf(o.y); hh.z = f2bf(o.z); hh.w = f2bf(o.w);
            reinterpret_cast<ushort4*>(outh + (size_t)b * NL * ND)[(size_t)t * 128 + c4] = hh;
        }
    }
}

// ---------------------------------------------------------------------------
extern "C" void kernel_launch(void* const* d_in, const int* in_sizes, int n_in,
                              void* d_out, int out_size, void* d_ws, size_t ws_size,
                              hipStream_t stream)
{
    const float* x  = (const float*)d_in[0];
    const float* Wq = (const float*)d_in[1];
    const float* bq = (const float*)d_in[2];  (void)bq;  // bias terms are
    const float* Wk = (const float*)d_in[3];             // tau-independent ->
    const float* bk = (const float*)d_in[4];  (void)bk;  // drop out of topk+softmax
    const float* Wv = (const float*)d_in[5];
    const float* bv = (const float*)d_in[6];
    const float* Wo = (const float*)d_in[7];
    const float* bo = (const float*)d_in[8];
    const float* Wd = (const float*)d_in[9];
    const float* bd = (const float*)d_in[10];
    float* out = (float*)d_out;

    // ---- workspace layout: 70 MiB total ----
    const size_t MBy = 1024ull * 1024ull;
    char* ws = (char*)d_ws;
    float* mc  = (float*)(ws);                 // 128 KB
    float* wts = (float*)(ws + 131072);        // 2 KB
    int*   dly = (int*)  (ws + 133120);        // 2 KB
    u16* Wq_h  = (u16*)(ws + 1 * MBy);
    u16* Wq_l  = (u16*)(ws + 1 * MBy + 512 * 1024);
    u16* Wk_h  = (u16*)(ws + 2 * MBy);
    u16* Wk_l  = (u16*)(ws + 2 * MBy + 512 * 1024);
    u16* Wvt_h = (u16*)(ws + 3 * MBy);
    u16* Wot_h = (u16*)(ws + 3 * MBy + 512 * 1024);
    u16* Wdt_h = (u16*)(ws + 4 * MBy);
    u16* Mt_h  = (u16*)(ws + 4 * MBy + 512 * 1024);
    u16* Mt_l  = (u16*)(ws + 5 * MBy);
    u16* ph    = (u16*)(ws + 6 * MBy);         // 32 MiB: P-hi -> v_bf -> x1s_bf
    u16* pl    = (u16*)(ws + 38 * MBy);        // 32 MiB: P-lo -> agg_bf
    u16* v_bf   = ph;
    u16* agg_bf = pl;
    u16* xsh    = ph;

    hipMemsetAsync(mc, 0, (size_t)NB * NL * sizeof(float), stream);

    prep_weights<<<dim3((ND * ND) / 256, 5), 256, 0, stream>>>(
        Wq, Wk, Wv, Wo, Wd, Wq_h, Wq_l, Wk_h, Wk_l, Wvt_h, Wot_h, Wdt_h);

    // Mt[f][e] = sum_c Wk[f][c]*Wq[e][c]  (both operands AS STORED), split out
    mm_mfma<3, 0, 0, 1, 0, 0><<<dim3(4, 4), 256, 0, stream>>>(
        Wk_h, Wk_l, nullptr, Wq_h, Wq_l, nullptr,
        nullptr, nullptr, nullptr, Mt_h, Mt_l, nullptr);

    const dim3 gg(ND / 128, (NB * NL) / 128);   // (4, 256)

    // P = x @ M  (A: fp32 x reg-split; B: Mt split) -> ph/pl
    mm_mfma<3, 1, 0, 1, 0, 0><<<gg, 256, 0, stream>>>(
        nullptr, nullptr, x, Mt_h, Mt_l, nullptr,
        nullptr, nullptr, nullptr, ph, pl, nullptr);

    // mean_corr: diag-reduce of P_b @ X_b^T (A: ph/pl; B: fp32 x reg-split)
    mm_mfma<3, 0, 1, 3, 0, 0><<<dim3(NL / 128, NL / 128, NB), 256, 0, stream>>>(
        ph, pl, nullptr, nullptr, nullptr, x,
        nullptr, nullptr, nullptr, nullptr, nullptr, mc);

    topk_softmax<<<NB, 256, 0, stream>>>(mc, wts, dly);

    // v = x @ Wv + bv -> v_bf (reuses ph; P dead after corr)
    mm_mfma<1, 1, 0, 2, 1, 0><<<gg, 256, 0, stream>>>(
        nullptr, nullptr, x, Wvt_h, nullptr, nullptr,
        bv, nullptr, nullptr, v_bf, nullptr, nullptr);

    // agg -> agg_bf (reuses pl)
    aggregate<<<dim3(NL / 4, NB), 256, 0, stream>>>(v_bf, wts, dly, agg_bf);

    // x1 = agg @ Wo + bo + x -> d_out (fp32)
    mm_mfma<1, 0, 0, 0, 1, 1><<<gg, 256, 0, stream>>>(
        agg_bf, nullptr, nullptr, Wot_h, nullptr, nullptr,
        bo, x, out, nullptr, nullptr, nullptr);

    // x1s = x1 - movavg(x1): in-place on d_out, bf16 copy -> xsh (v dead)
    movavg_ip<1><<<dim3(128, NB), 256, 0, stream>>>(out, xsh);

    // x2 = x1s @ Wd + bd + x1s: A = xsh (bf16), residual = d_out (fp32),
    // written back to d_out (same-thread read-then-write per element: safe)
    mm_mfma<1, 0, 0, 0, 1, 1><<<gg, 256, 0, stream>>>(
        xsh, nullptr, nullptr, Wdt_h, nullptr, nullptr,
        bd, out, out, nullptr, nullptr, nullptr);

    // out = x2 - movavg(x2): in-place on d_out
    movavg_ip<0><<<dim3(128, NB), 256, 0, stream>>>(out, nullptr);
}

// Round 7
// 709.040 us; speedup vs baseline: 1.4421x; 1.4342x over previous
//
#include <hip/hip_runtime.h>
#include <stdint.h>

#define NB 32
#define NL 1024
#define ND 512
#define NTOP 13

typedef unsigned short u16;
typedef __bf16 bf16x8 __attribute__((ext_vector_type(8)));
typedef float f32x4 __attribute__((ext_vector_type(4)));

__device__ __forceinline__ u16 f2bf(float f) {
    union { float f; uint32_t u; } v; v.f = f;
    uint32_t r = v.u + 0x7fffu + ((v.u >> 16) & 1u);
    return (u16)(r >> 16);
}
__device__ __forceinline__ float bf2f(u16 h) {
    union { uint32_t u; float f; } v; v.u = ((uint32_t)h) << 16;
    return v.f;
}

__device__ __forceinline__ void gload16(const void* g, void* l) {
    __builtin_amdgcn_global_load_lds(
        (__attribute__((address_space(1))) void*)g,
        (__attribute__((address_space(3))) void*)l, 16, 0, 0);
}

// ---------------------------------------------------------------------------
// MFMA tile kernel: C[m][n] = sum_k A[m][k] * Bt[n][k]  (K = ND = 512, all
// operands row-major bf16 with inner stride ND, staged via global_load_lds
// ONLY - no VALU in the staging path).
//
// LDS XOR-swizzle (kills the 8-way ds_read_b128 conflict; measured 0
// conflicts in r6): physical 16B slot = logical ^ ((row>>1)&3); writes stay
// linear, the per-lane GLOBAL source column is pre-swizzled instead.
//
// XCD-aware block remap (T1): all launch grids have nwg % 8 == 0; tiles
// sharing operand panels land on the same XCD's L2.
//
// PASSES: 1 = plain bf16 (hi only); 3 = split hi/lo (hh + lh + hl).
// OUT_MODE: 0 = fp32 out; 1 = split bf16 out (Oh,Ol); 2 = bf16 out (Oh);
//           3 = correlation diag-reduce into mc (batched via blockIdx.z).
// HAS_BIAS: add bias[col].  RESID: add fp32 Rf[idx] (may alias Of:
//           same-thread read-then-write per element only).
// ---------------------------------------------------------------------------
template <int PASSES, int OUT_MODE, int HAS_BIAS, int RESID>
__global__ __launch_bounds__(256) void mm_mfma(
    const u16* __restrict__ Ah, const u16* __restrict__ Al,
    const u16* __restrict__ Bh, const u16* __restrict__ Bl,
    const float* __restrict__ bias, const float* __restrict__ Rf,
    float* __restrict__ Of, u16* __restrict__ Oh, u16* __restrict__ Ol,
    float* __restrict__ mc)
{
    constexpr int NBUF = (PASSES == 3) ? 4 : 2;
    __shared__ u16 lds[NBUF][4096];   // [buf][row*32 + slot*8], 8 KB each

    // ---- XCD-aware remap (bijective: nwg % 8 == 0 for all our grids) ----
    const int gx = gridDim.x, gy = gridDim.y;
    const int nwg = gx * gy * gridDim.z;
    const int lin = (blockIdx.z * gy + blockIdx.y) * gx + blockIdx.x;
    const int cpx = nwg >> 3;
    int swz = (lin & 7) * cpx + (lin >> 3);
    const int bx = swz % gx; swz /= gx;
    const int by = swz % gy;
    const int bz = swz / gy;

    const int tid  = threadIdx.x;
    const int lane = tid & 63;
    const int wid  = tid >> 6;
    const int wr = wid >> 1, wc = wid & 1;

    const int n0 = bx * 128;
    const int m0 = by * 128;
    const size_t boff = (size_t)bz * NL * ND;   // 0 unless batched (corr)

    f32x4 acc[4][4];
#pragma unroll
    for (int m = 0; m < 4; ++m)
#pragma unroll
        for (int n = 0; n < 4; ++n) acc[m][n] = (f32x4){0.f, 0.f, 0.f, 0.f};

    const int srow = tid >> 2;                        // 0..63 staging row
    const int scol = ((tid & 3) ^ ((tid >> 3) & 3)) * 8;  // swizzled src col
    const int lo16 = lane & 15;
    const int hi16 = lane >> 4;
    const int c16r = hi16 ^ ((lo16 >> 1) & 3);        // swizzled read slot

    for (int k0 = 0; k0 < ND; k0 += 32) {
#pragma unroll
        for (int i = 0; i < 2; ++i) {
            const int ro   = i * 64 + srow;
            const int ldso = i * 2048 + wid * 512;    // wave-uniform dest (elems)
            const size_t ga = boff + (size_t)(m0 + ro) * ND + k0 + scol;
            const size_t gb = boff + (size_t)(n0 + ro) * ND + k0 + scol;
            gload16(Ah + ga, &lds[0][ldso]);
            gload16(Bh + gb, &lds[1][ldso]);
            if constexpr (PASSES == 3) {
                gload16(Al + ga, &lds[2][ldso]);
                gload16(Bl + gb, &lds[3][ldso]);
            }
        }
        __syncthreads();

        bf16x8 ah[4], bh[4], al[4], bl[4];
#pragma unroll
        for (int m = 0; m < 4; ++m) {
            const int off = (wr * 64 + m * 16 + lo16) * 32 + c16r * 8;
            ah[m] = *reinterpret_cast<const bf16x8*>(&lds[0][off]);
            if constexpr (PASSES == 3)
                al[m] = *reinterpret_cast<const bf16x8*>(&lds[2][off]);
        }
#pragma unroll
        for (int n = 0; n < 4; ++n) {
            const int off = (wc * 64 + n * 16 + lo16) * 32 + c16r * 8;
            bh[n] = *reinterpret_cast<const bf16x8*>(&lds[1][off]);
            if constexpr (PASSES == 3)
                bl[n] = *reinterpret_cast<const bf16x8*>(&lds[3][off]);
        }
#pragma unroll
        for (int m = 0; m < 4; ++m)
#pragma unroll
            for (int n = 0; n < 4; ++n) {
                acc[m][n] = __builtin_amdgcn_mfma_f32_16x16x32_bf16(ah[m], bh[n], acc[m][n], 0, 0, 0);
                if constexpr (PASSES == 3) {
                    acc[m][n] = __builtin_amdgcn_mfma_f32_16x16x32_bf16(al[m], bh[n], acc[m][n], 0, 0, 0);
                    acc[m][n] = __builtin_amdgcn_mfma_f32_16x16x32_bf16(ah[m], bl[n], acc[m][n], 0, 0, 0);
                }
            }
        __syncthreads();
    }

    if constexpr (OUT_MODE == 3) {
        float* diag = reinterpret_cast<float*>(&lds[0][0]);  // 4 KB scratch
        for (int s = tid; s < NL; s += 256) diag[s] = 0.f;
        __syncthreads();
#pragma unroll
        for (int m = 0; m < 4; ++m)
#pragma unroll
            for (int n = 0; n < 4; ++n)
#pragma unroll
                for (int r = 0; r < 4; ++r) {
                    int row = m0 + wr * 64 + m * 16 + hi16 * 4 + r;
                    int col = n0 + wc * 64 + n * 16 + lo16;
                    atomicAdd(&diag[(row - col) & (NL - 1)], acc[m][n][r]);
                }
        __syncthreads();
        const int base = (m0 - n0 - 127) & (NL - 1);
        float* mcb = mc + (size_t)bz * NL;
        for (int o = tid; o < 255; o += 256) {
            int tau = (base + o) & (NL - 1);
            atomicAdd(&mcb[tau], diag[tau] * (1.0f / (float)ND));
        }
    } else {
#pragma unroll
        for (int m = 0; m < 4; ++m)
#pragma unroll
            for (int n = 0; n < 4; ++n)
#pragma unroll
                for (int r = 0; r < 4; ++r) {
                    const int row = m0 + wr * 64 + m * 16 + hi16 * 4 + r;
                    const int col = n0 + wc * 64 + n * 16 + lo16;
                    const size_t idx = (size_t)row * ND + col;
                    float v = acc[m][n][r];
                    if constexpr (HAS_BIAS) v += bias[col];
                    if constexpr (RESID) v += Rf[idx];
                    if constexpr (OUT_MODE == 0) {
                        Of[idx] = v;
                    } else if constexpr (OUT_MODE == 1) {
                        u16 h = f2bf(v);
                        Oh[idx] = h;
                        Ol[idx] = f2bf(v - bf2f(h));
                    } else {
                        Oh[idx] = f2bf(v);
                    }
                }
    }
}

// ---------------------------------------------------------------------------
// x (fp32) -> xh, xl (split bf16), 4 elems/thread. Outputs live in d_out.
// ---------------------------------------------------------------------------
__global__ __launch_bounds__(256) void split_x(
    const float* __restrict__ x, u16* __restrict__ xh, u16* __restrict__ xl)
{
    const size_t i = (size_t)blockIdx.x * 256 + threadIdx.x;
    float4 v = reinterpret_cast<const float4*>(x)[i];
    ushort4 h, l;
    h.x = f2bf(v.x); l.x = f2bf(v.x - bf2f(h.x));
    h.y = f2bf(v.y); l.y = f2bf(v.y - bf2f(h.y));
    h.z = f2bf(v.z); l.z = f2bf(v.z - bf2f(h.z));
    h.w = f2bf(v.w); l.w = f2bf(v.w - bf2f(h.w));
    reinterpret_cast<ushort4*>(xh)[i] = h;
    reinterpret_cast<ushort4*>(xl)[i] = l;
}

// ---------------------------------------------------------------------------
// Weight prep. w==0/1: Wq/Wk split UNtransposed (M-GEMM contracts over the
// OUTPUT dim of both). w==2/3/4: Wv/Wo/Wd transposed hi-only.
// ---------------------------------------------------------------------------
__global__ __launch_bounds__(256) void prep_weights(
    const float* __restrict__ Wq, const float* __restrict__ Wk,
    const float* __restrict__ Wv, const float* __restrict__ Wo,
    const float* __restrict__ Wd,
    u16* __restrict__ wq_h, u16* __restrict__ wq_l,
    u16* __restrict__ wk_h, u16* __restrict__ wk_l,
    u16* __restrict__ wvt_h, u16* __restrict__ wot_h, u16* __restrict__ wdt_h)
{
    const int idx = blockIdx.x * 256 + threadIdx.x;   // 0..262143
    const int w = blockIdx.y;
    if (w == 0) {
        float val = Wq[idx];
        u16 h = f2bf(val);
        wq_h[idx] = h; wq_l[idx] = f2bf(val - bf2f(h));
    } else if (w == 1) {
        float val = Wk[idx];
        u16 h = f2bf(val);
        wk_h[idx] = h; wk_l[idx] = f2bf(val - bf2f(h));
    } else {
        const int n = idx >> 9;
        const int k = idx & (ND - 1);
        const float* W = (w == 2) ? Wv : (w == 3) ? Wo : Wd;
        float val = W[(size_t)k * ND + n];
        u16 h = f2bf(val);
        if (w == 2)      { wvt_h[idx] = h; }
        else if (w == 3) { wot_h[idx] = h; }
        else             { wdt_h[idx] = h; }
    }
}

// ---------------------------------------------------------------------------
// Per-batch top-13 (argmax iteration, ties -> lower index) + softmax.
// ---------------------------------------------------------------------------
__global__ __launch_bounds__(256) void topk_softmax(
    const float* __restrict__ mc, float* __restrict__ wout, int* __restrict__ dout)
{
    const int tid = threadIdx.x;
    const int b = blockIdx.x;
    __shared__ float vals[NL];
    __shared__ float rv[256];
    __shared__ int   ri[256];
    __shared__ float topv[NTOP];
    __shared__ int   topi[NTOP];

    for (int s = tid; s < NL; s += 256) vals[s] = mc[b * NL + s];
    __syncthreads();

    for (int it = 0; it < NTOP; ++it) {
        float bv = -3.402823466e38f;
        int bi = 1 << 30;
        for (int s = tid; s < NL; s += 256) {
            float vv = vals[s];
            if (vv > bv || (vv == bv && s < bi)) { bv = vv; bi = s; }
        }
        rv[tid] = bv; ri[tid] = bi;
        __syncthreads();
        for (int off = 128; off > 0; off >>= 1) {
            if (tid < off) {
                float ov = rv[tid + off]; int oi = ri[tid + off];
                if (ov > rv[tid] || (ov == rv[tid] && oi < ri[tid])) { rv[tid] = ov; ri[tid] = oi; }
            }
            __syncthreads();
        }
        if (tid == 0) { topv[it] = rv[0]; topi[it] = ri[0]; vals[ri[0]] = -3.402823466e38f; }
        __syncthreads();
    }

    if (tid == 0) {
        float m = topv[0];
        float e[NTOP];
        float ssum = 0.f;
        for (int i = 0; i < NTOP; ++i) { e[i] = expf(topv[i] - m); ssum += e[i]; }
        float inv = 1.0f / ssum;
        for (int i = 0; i < NTOP; ++i) {
            wout[b * 16 + i] = e[i] * inv;
            dout[b * 16 + i] = topi[i];
        }
    }
}

// ---------------------------------------------------------------------------
// agg[b,t,c] = sum_i w[b,i] * v[b,(t+delay[b,i])%L, c]; v & agg bf16.
// ---------------------------------------------------------------------------
__global__ __launch_bounds__(256) void aggregate(
    const u16* __restrict__ v, const float* __restrict__ wts,
    const int* __restrict__ dly, u16* __restrict__ out)
{
    const int tid = threadIdx.x;
    const int b = blockIdx.y;
    const int t = blockIdx.x * 4 + (tid >> 6);
    const int c8 = tid & 63;
    const uint4* vb = reinterpret_cast<const uint4*>(v + (size_t)b * NL * ND);
    float acc[8] = {0.f};
#pragma unroll
    for (int i = 0; i < NTOP; ++i) {
        const int s = (t + dly[b * 16 + i]) & (NL - 1);
        const float wi = wts[b * 16 + i];
        uint4 p = vb[(size_t)s * 64 + c8];
        const uint32_t pw[4] = {p.x, p.y, p.z, p.w};
#pragma unroll
        for (int j = 0; j < 4; ++j) {
            acc[2 * j]     = fmaf(wi, bf2f((u16)(pw[j] & 0xffff)), acc[2 * j]);
            acc[2 * j + 1] = fmaf(wi, bf2f((u16)(pw[j] >> 16)),    acc[2 * j + 1]);
        }
    }
    uint32_t o[4];
#pragma unroll
    for (int j = 0; j < 4; ++j)
        o[j] = (uint32_t)f2bf(acc[2 * j]) | ((uint32_t)f2bf(acc[2 * j + 1]) << 16);
    reinterpret_cast<uint4*>(out + (size_t)b * NL * ND)[(size_t)t * 64 + c8] =
        make_uint4(o[0], o[1], o[2], o[3]);
}

// ---------------------------------------------------------------------------
// IN-PLACE series decomp, COALESCED: block owns 8 float4-columns (32 ch) x
// full L of one batch. Loads coalesced 128B segments into padded LDS
// ([NL][9] float4 - conflict-free), sliding-window sum per thread
// (c = tid&7, 32 consecutive t each), TF 'SAME' edge-count correction.
// WRITE_BF: also emit bf16(hi) copy for the next GEMM's A operand.
// ---------------------------------------------------------------------------
template <int WRITE_BF>
__global__ __launch_bounds__(256) void movavg_ip(
    float* __restrict__ io, u16* __restrict__ outh)
{
    __shared__ float4 col[NL][9];   // padded: 144 KB
    const int tid = threadIdx.x;
    const int g = blockIdx.x;       // 0..15 column group (8 float4 = 32 ch)
    const int b = blockIdx.y;
    float4* base = reinterpret_cast<float4*>(io + (size_t)b * NL * ND) + g * 8;

    for (int i = tid; i < NL * 8; i += 256) {
        const int t = i >> 3, c = i & 7;
        col[t][c] = base[(size_t)t * 128 + c];
    }
    __syncthreads();

    const int c  = tid & 7;
    const int t0 = (tid >> 3) * 32;
    int lo = t0 - 12; if (lo < 0) lo = 0;
    int hi = t0 + 12;                      // t0+12 <= 1004 < NL always
    float4 s = {0.f, 0.f, 0.f, 0.f};
    for (int u = lo; u <= hi; ++u) {
        float4 p = col[u][c];
        s.x += p.x; s.y += p.y; s.z += p.z; s.w += p.w;
    }
#pragma unroll 4
    for (int t = t0; t < t0 + 32; ++t) {
        const float inv = 1.0f / (float)(hi - lo + 1);
        float4 cv = col[t][c];
        float4 o = {cv.x - s.x * inv, cv.y - s.y * inv,
                    cv.z - s.z * inv, cv.w - s.w * inv};
        base[(size_t)t * 128 + c] = o;
        if constexpr (WRITE_BF) {
            ushort4 hh;
            hh.x = f2bf(o.x); hh.y = f2bf(o.y); hh.z = f2bf(o.z); hh.w = f2bf(o.w);
            reinterpret_cast<ushort4*>(outh + (size_t)b * NL * ND + (size_t)t * ND)[g * 8 + c] = hh;
        }
        // advance window to t+1
        const int nhi = t + 13;
        if (nhi <= NL - 1) {
            float4 p = col[nhi][c];
            s.x += p.x; s.y += p.y; s.z += p.z; s.w += p.w;
            hi = nhi;
        }
        if (t - 11 > 0) {
            float4 p = col[lo][c];
            s.x -= p.x; s.y -= p.y; s.z -= p.z; s.w -= p.w;
            lo = t - 11;
        }
    }
}

// ---------------------------------------------------------------------------
extern "C" void kernel_launch(void* const* d_in, const int* in_sizes, int n_in,
                              void* d_out, int out_size, void* d_ws, size_t ws_size,
                              hipStream_t stream)
{
    const float* x  = (const float*)d_in[0];
    const float* Wq = (const float*)d_in[1];
    const float* bq = (const float*)d_in[2];  (void)bq;  // bias terms are
    const float* Wk = (const float*)d_in[3];             // tau-independent ->
    const float* bk = (const float*)d_in[4];  (void)bk;  // drop out of topk+softmax
    const float* Wv = (const float*)d_in[5];
    const float* bv = (const float*)d_in[6];
    const float* Wo = (const float*)d_in[7];
    const float* bo = (const float*)d_in[8];
    const float* Wd = (const float*)d_in[9];
    const float* bd = (const float*)d_in[10];
    float* out = (float*)d_out;

    // ---- workspace layout: 70 MiB total (unchanged from r5/r6) ----
    const size_t MBy = 1024ull * 1024ull;
    char* ws = (char*)d_ws;
    float* mc  = (float*)(ws);                 // 128 KB
    float* wts = (float*)(ws + 131072);        // 2 KB
    int*   dly = (int*)  (ws + 133120);        // 2 KB
    u16* Wq_h  = (u16*)(ws + 1 * MBy);
    u16* Wq_l  = (u16*)(ws + 1 * MBy + 512 * 1024);
    u16* Wk_h  = (u16*)(ws + 2 * MBy);
    u16* Wk_l  = (u16*)(ws + 2 * MBy + 512 * 1024);
    u16* Wvt_h = (u16*)(ws + 3 * MBy);
    u16* Wot_h = (u16*)(ws + 3 * MBy + 512 * 1024);
    u16* Wdt_h = (u16*)(ws + 4 * MBy);
    u16* Mt_h  = (u16*)(ws + 4 * MBy + 512 * 1024);
    u16* Mt_l  = (u16*)(ws + 5 * MBy);
    u16* ph    = (u16*)(ws + 6 * MBy);         // 32 MiB: P-hi -> v_bf -> x1s_bf
    u16* pl    = (u16*)(ws + 38 * MBy);        // 32 MiB: P-lo -> agg_bf
    u16* v_bf   = ph;
    u16* agg_bf = pl;
    u16* xsh    = ph;

    // xh/xl live in d_out (dead once the Wo-GEMM writes x1 there)
    u16* xh = (u16*)out;
    u16* xl = xh + (size_t)NB * NL * ND;

    hipMemsetAsync(mc, 0, (size_t)NB * NL * sizeof(float), stream);

    prep_weights<<<dim3((ND * ND) / 256, 5), 256, 0, stream>>>(
        Wq, Wk, Wv, Wo, Wd, Wq_h, Wq_l, Wk_h, Wk_l, Wvt_h, Wot_h, Wdt_h);

    split_x<<<(NB * NL * ND) / 4 / 256, 256, 0, stream>>>(x, xh, xl);

    // Mt[f][e] = sum_c Wk[f][c]*Wq[e][c] (both AS STORED), split bf16 out
    mm_mfma<3, 1, 0, 0><<<dim3(4, 4), 256, 0, stream>>>(
        Wk_h, Wk_l, Wq_h, Wq_l, nullptr, nullptr,
        nullptr, Mt_h, Mt_l, nullptr);

    const dim3 gg(ND / 128, (NB * NL) / 128);   // (4, 256)

    // P = x @ M  (pure gload_lds staging both sides) -> ph/pl
    mm_mfma<3, 1, 0, 0><<<gg, 256, 0, stream>>>(
        xh, xl, Mt_h, Mt_l, nullptr, nullptr,
        nullptr, ph, pl, nullptr);

    // mean_corr: diag-reduce of P_b @ X_b^T
    mm_mfma<3, 3, 0, 0><<<dim3(NL / 128, NL / 128, NB), 256, 0, stream>>>(
        ph, pl, xh, xl, nullptr, nullptr,
        nullptr, nullptr, nullptr, mc);

    topk_softmax<<<NB, 256, 0, stream>>>(mc, wts, dly);

    // v = x @ Wv + bv -> v_bf (reuses ph; P dead after corr)
    mm_mfma<1, 2, 1, 0><<<gg, 256, 0, stream>>>(
        xh, nullptr, Wvt_h, nullptr, bv, nullptr,
        nullptr, v_bf, nullptr, nullptr);

    // agg -> agg_bf (reuses pl)
    aggregate<<<dim3(NL / 4, NB), 256, 0, stream>>>(v_bf, wts, dly, agg_bf);

    // x1 = agg @ Wo + bo + x -> d_out (overwrites xh/xl: dead)
    mm_mfma<1, 0, 1, 1><<<gg, 256, 0, stream>>>(
        agg_bf, nullptr, Wot_h, nullptr, bo, x,
        out, nullptr, nullptr, nullptr);

    // x1s = x1 - movavg(x1): in-place on d_out, bf16 copy -> xsh (v dead)
    movavg_ip<1><<<dim3(16, NB), 256, 0, stream>>>(out, xsh);

    // x2 = x1s @ Wd + bd + x1s (residual aliases output: same-thread RMW)
    mm_mfma<1, 0, 1, 1><<<gg, 256, 0, stream>>>(
        xsh, nullptr, Wdt_h, nullptr, bd, out,
        out, nullptr, nullptr, nullptr);

    // out = x2 - movavg(x2): in-place on d_out
    movavg_ip<0><<<dim3(16, NB), 256, 0, stream>>>(out, nullptr);
}